// Round 14
// baseline (380.399 us; speedup 1.0000x reference)
//
#include <hip/hip_runtime.h>
#include <hip/hip_bf16.h>
#include <math.h>

#define N_NODES 16384
#define C_IN 32

typedef __attribute__((ext_vector_type(8))) short short8;
typedef __attribute__((ext_vector_type(4))) short s16x4;
typedef __attribute__((ext_vector_type(4))) float f32x4;
typedef __attribute__((ext_vector_type(4))) float f4v;

__device__ __forceinline__ unsigned short f2bf(float f) {
    unsigned u = __float_as_uint(f);
    u = u + 0x7fffu + ((u >> 16) & 1u);   // RNE to bf16
    return (unsigned short)(u >> 16);
}

// ---------------------------------------------------------------------------
// K0: zero gc[32]
// ---------------------------------------------------------------------------
__global__ void k_zero(float* __restrict__ p) {
    p[threadIdx.x] = 0.f;
}

// ---------------------------------------------------------------------------
// K1 v2: attention scores, 32 nodes per 256-thread block (512 blocks).
// Weight staging (12KB) amortized over 4x more nodes than v1.
// 8 lane-groups of 32; each group computes 4 consecutive nodes.
// ---------------------------------------------------------------------------
__global__ __launch_bounds__(256) void k_attn_scores(
    const float* __restrict__ x,
    const float* __restrict__ aw1, const float* __restrict__ ab1,
    const float* __restrict__ aw2, const float* __restrict__ ab2,
    const float* __restrict__ aw3, const float* __restrict__ ab3,
    float* __restrict__ scores)
{
    __shared__ float w1s[4096];   // [32][128]
    __shared__ float w2s[8192];   // [128][64]
    __shared__ float b1s[128];
    __shared__ float b2s[64];
    __shared__ float w3s[64];
    __shared__ float xs[1024];    // 32 nodes x 32 ch
    __shared__ float h1s[4096];   // 32 nodes x 128

    const int tid = threadIdx.x;
    for (int i = tid; i < 4096; i += 256) w1s[i] = aw1[i];
    for (int i = tid; i < 8192; i += 256) w2s[i] = aw2[i];
    if (tid < 128) b1s[tid] = ab1[tid];
    if (tid < 64)  { b2s[tid] = ab2[tid]; w3s[tid] = aw3[tid]; }
    #pragma unroll
    for (int i = 0; i < 4; ++i)
        xs[tid + 256 * i] = x[(size_t)blockIdx.x * 1024 + tid + 256 * i];
    __syncthreads();

    const int g   = tid >> 5;   // lane-group 0..7 -> nodes g*4..g*4+3
    const int t31 = tid & 31;

    // layer 1: 4 nodes x 4 consecutive outputs per thread
    float a0[4], a1[4], a2[4], a3[4];
    #pragma unroll
    for (int nn = 0; nn < 4; ++nn) {
        a0[nn] = b1s[t31*4+0]; a1[nn] = b1s[t31*4+1];
        a2[nn] = b1s[t31*4+2]; a3[nn] = b1s[t31*4+3];
    }
    #pragma unroll
    for (int c = 0; c < 32; ++c) {
        float4 w = *(const float4*)&w1s[c*128 + t31*4];
        #pragma unroll
        for (int nn = 0; nn < 4; ++nn) {
            float xv = xs[(g*4 + nn)*32 + c];
            a0[nn] += xv * w.x; a1[nn] += xv * w.y;
            a2[nn] += xv * w.z; a3[nn] += xv * w.w;
        }
    }
    #pragma unroll
    for (int nn = 0; nn < 4; ++nn)
        *(float4*)&h1s[(g*4 + nn)*128 + t31*4] =
            make_float4(fmaxf(a0[nn],0.f), fmaxf(a1[nn],0.f),
                        fmaxf(a2[nn],0.f), fmaxf(a3[nn],0.f));
    __syncthreads();

    // layer 2 + dot with w3: 4 nodes x 2 outputs per thread
    float c0[4], c1[4];
    #pragma unroll
    for (int nn = 0; nn < 4; ++nn) { c0[nn] = b2s[t31*2]; c1[nn] = b2s[t31*2+1]; }
    #pragma unroll 4
    for (int o = 0; o < 128; ++o) {
        float2 w = *(const float2*)&w2s[o*64 + t31*2];
        #pragma unroll
        for (int nn = 0; nn < 4; ++nn) {
            float hv = h1s[(g*4 + nn)*128 + o];
            c0[nn] += hv * w.x;
            c1[nn] += hv * w.y;
        }
    }
    #pragma unroll
    for (int nn = 0; nn < 4; ++nn) {
        float s = fmaxf(c0[nn], 0.f) * w3s[t31*2] + fmaxf(c1[nn], 0.f) * w3s[t31*2 + 1];
        s += __shfl_xor(s, 1);  s += __shfl_xor(s, 2);  s += __shfl_xor(s, 4);
        s += __shfl_xor(s, 8);  s += __shfl_xor(s, 16);
        if (t31 == 0) scores[(size_t)blockIdx.x * 32 + g*4 + nn] = s + ab3[0];
    }
}

// ---------------------------------------------------------------------------
// K2: softmax max + sum(exp) over 16384 scores, single block
// ---------------------------------------------------------------------------
__global__ __launch_bounds__(1024) void k_softmax_red(
    const float* __restrict__ scores, float* __restrict__ red)
{
    __shared__ float sm[1024];
    const int tid = threadIdx.x;
    float m = -3.4e38f;
    for (int i = tid; i < N_NODES; i += 1024) m = fmaxf(m, scores[i]);
    sm[tid] = m; __syncthreads();
    for (int s = 512; s > 0; s >>= 1) {
        if (tid < s) sm[tid] = fmaxf(sm[tid], sm[tid + s]);
        __syncthreads();
    }
    m = sm[0];
    __syncthreads();
    float acc = 0.f;
    for (int i = tid; i < N_NODES; i += 1024) acc += expf(scores[i] - m);
    sm[tid] = acc; __syncthreads();
    for (int s = 512; s > 0; s >>= 1) {
        if (tid < s) sm[tid] += sm[tid + s];
        __syncthreads();
    }
    if (tid == 0) { red[0] = m; red[1] = sm[0]; }
}

// ---------------------------------------------------------------------------
// K3: attn = softmax(scores); wfT(bf16, transposed [32][16384]); gc = sum(wf)
// ---------------------------------------------------------------------------
__global__ __launch_bounds__(256) void k_attn_wf(
    const float* __restrict__ scores, const float* __restrict__ red,
    const float* __restrict__ x, float* __restrict__ attn,
    unsigned short* __restrict__ wfT, float* __restrict__ gc)
{
    const int n = blockIdx.x * 256 + threadIdx.x;
    const float m = red[0], s = red[1];
    const float a = expf(scores[n] - m) / s;
    attn[n] = a;

    float wv[32];
    const float4* xr = (const float4*)(x + (size_t)n * 32);
    #pragma unroll
    for (int q = 0; q < 8; ++q) {
        float4 v = xr[q];
        wv[q*4+0] = v.x * a; wv[q*4+1] = v.y * a;
        wv[q*4+2] = v.z * a; wv[q*4+3] = v.w * a;
    }
    #pragma unroll
    for (int c = 0; c < 32; ++c)
        wfT[(size_t)c * N_NODES + n] = f2bf(wv[c]);   // coalesced per c

    const int lane = threadIdx.x & 63;
    #pragma unroll
    for (int c = 0; c < 32; ++c) {
        float v = wv[c];
        v += __shfl_xor(v, 1);  v += __shfl_xor(v, 2);  v += __shfl_xor(v, 4);
        v += __shfl_xor(v, 8);  v += __shfl_xor(v, 16); v += __shfl_xor(v, 32);
        if (lane == 0) atomicAdd(&gc[c], v);
    }
}

// ---------------------------------------------------------------------------
// K5 v7 (unchanged from round 13 measurement): bulk + TLP, js in low bits.
// ---------------------------------------------------------------------------
__global__ __launch_bounds__(256, 3) void k_context(
    const float* __restrict__ A, const unsigned short* __restrict__ wfT,
    const float* __restrict__ x, const float* __restrict__ attn,
    float* __restrict__ partials)
{
    __shared__ unsigned short sB_u[32 * 256];    // 16 KB, XOR-swizzled
    __shared__ short sA[4][16 * 256];            // 32 KB: per-wave 16 rows x 256
    __shared__ float sRed[4];

    const int tid   = threadIdx.x;
    const int wid   = tid >> 6, lane = tid & 63;
    const int js    = blockIdx.x & 63;    // 64 col-splits of 256  (LOW bits)
    const int rb    = blockIdx.x >> 6;    // 256 row-blocks of 64 rows
    const int i0    = rb * 64 + wid * 16;
    const int gcol0 = js * 256;

    const int q   = lane >> 4;
    const int r16 = lane & 15;
    char* wbase = (char*)sA[wid];

    // ---- issue A loads FIRST: 16 instructions, each one full row = 1KB ----
    f4v av[16];
    #pragma unroll
    for (int r = 0; r < 16; ++r)
        av[r] = __builtin_nontemporal_load(
            (const f4v*)(A + (size_t)(i0 + r) * N_NODES + gcol0 + lane * 4));

    // ---- stage B slice (L2-resident wfT): 32 rows x 512B, swizzled ----
    {
        const int row = tid >> 3;                 // 0..31
        const unsigned short* gB = wfT + (size_t)row * N_NODES + gcol0;
        char* lB = (char*)sB_u + row * 512;
        #pragma unroll
        for (int c = 0; c < 4; ++c) {
            const int chunk = (tid & 7) + 8 * c;  // 0..31, 16B each
            short8 v = *(const short8*)(gB + chunk * 8);
            *(short8*)(lB + ((chunk * 16) ^ ((row & 7) << 4))) = v;
        }
    }
    __syncthreads();   // B visible to all waves (also implies vmcnt drain of A)

    // ---- cvt + write A rows into wave-private LDS (8B/lane, swizzled) ----
    #pragma unroll
    for (int r = 0; r < 16; ++r) {
        s16x4 w;
        w[0] = (short)f2bf(av[r][0]); w[1] = (short)f2bf(av[r][1]);
        w[2] = (short)f2bf(av[r][2]); w[3] = (short)f2bf(av[r][3]);
        *(s16x4*)(wbase + r * 512 + ((lane * 8) ^ ((r & 7) << 4))) = w;
    }

    // ---- MFMA: 8 k-slices x 2 channel-halves (wave-private A, shared B) ----
    f32x4 acc0 = {0.f, 0.f, 0.f, 0.f};
    f32x4 acc1 = {0.f, 0.f, 0.f, 0.f};
    const int swzA = (r16 & 7) << 4;
    const char* sBb = (const char*)sB_u;
    #pragma unroll
    for (int kk = 0; kk < 8; ++kk) {
        const int fo = kk * 64 + q * 16;
        short8 afr = *(const short8*)(wbase + r16 * 512 + (fo ^ swzA));
        short8 b0  = *(const short8*)(sBb + r16 * 512        + (fo ^ swzA));
        short8 b1  = *(const short8*)(sBb + (r16 + 16) * 512 + (fo ^ swzA));
        acc0 = __builtin_amdgcn_mfma_f32_16x16x32_bf16(afr, b0, acc0, 0, 0, 0);
        acc1 = __builtin_amdgcn_mfma_f32_16x16x32_bf16(afr, b1, acc1, 0, 0, 0);
    }

    // ---- epilogue: D[row=q*4+r, col=r16]; dot with wf = x*attn, reduce ----
    float partial = 0.f;
    #pragma unroll
    for (int r = 0; r < 4; ++r) {
        const int i = i0 + q * 4 + r;
        const float a = attn[i];
        partial += acc0[r] * (x[(size_t)i * 32 + r16]      * a);
        partial += acc1[r] * (x[(size_t)i * 32 + 16 + r16] * a);
    }
    partial += __shfl_xor(partial, 1);  partial += __shfl_xor(partial, 2);
    partial += __shfl_xor(partial, 4);  partial += __shfl_xor(partial, 8);
    partial += __shfl_xor(partial, 16); partial += __shfl_xor(partial, 32);
    if (lane == 0) sRed[wid] = partial;
    __syncthreads();
    if (tid == 0) partials[blockIdx.x] = (sRed[0] + sRed[1]) + (sRed[2] + sRed[3]);
}

// ---------------------------------------------------------------------------
// K5b DIAGNOSTIC read probe: linear read of A's first 536 MB (half of A).
// Each block reads one contiguous 256KB span; device-wide access is fully
// sequential. Plain (non-nt) loads. Sum kept live via partials2 store.
// Purpose: measure the true read-only HBM ceiling; duration is extracted by
// differencing the run total vs round 13 (~290 us).
// ---------------------------------------------------------------------------
__global__ __launch_bounds__(256) void k_readprobe(
    const float* __restrict__ A, float* __restrict__ p2)
{
    __shared__ float sr[4];
    const int tid = threadIdx.x;
    const float* base = A + (size_t)blockIdx.x * 65536 + tid * 4;
    float s = 0.f;
    #pragma unroll 8
    for (int k = 0; k < 64; ++k) {
        f4v v = *(const f4v*)(base + (size_t)k * 1024);
        s += (v[0] + v[1]) + (v[2] + v[3]);
    }
    s += __shfl_xor(s, 1);  s += __shfl_xor(s, 2);  s += __shfl_xor(s, 4);
    s += __shfl_xor(s, 8);  s += __shfl_xor(s, 16); s += __shfl_xor(s, 32);
    if ((tid & 63) == 0) sr[tid >> 6] = s;
    __syncthreads();
    if (tid == 0) p2[blockIdx.x] = (sr[0] + sr[1]) + (sr[2] + sr[3]);
}

// ---------------------------------------------------------------------------
// K6a: reduce partials[16384] -> cs; h1 for gc and gc2 = gc + 0.001*(cs/N)
// ---------------------------------------------------------------------------
__global__ __launch_bounds__(1024) void k_mlp1(
    const float* __restrict__ gc, const float* __restrict__ partials,
    const float* __restrict__ w1, const float* __restrict__ b1,
    float* __restrict__ h1ab)
{
    __shared__ float sm[1024];
    __shared__ float g1[32], g2[32];
    const int t = threadIdx.x;
    float acc = 0.f;
    #pragma unroll
    for (int i = 0; i < 16; ++i) acc += partials[t + 1024 * i];
    sm[t] = acc; __syncthreads();
    for (int s = 512; s > 0; s >>= 1) {
        if (t < s) sm[t] += sm[t + s];
        __syncthreads();
    }
    if (t < 32) {
        float cs = sm[0] * (1.0f / 16384.0f);
        g1[t] = gc[t];
        g2[t] = gc[t] + 0.001f * cs;
    }
    __syncthreads();
    float s1 = b1[t], s2 = b1[t];
    #pragma unroll
    for (int c = 0; c < 32; ++c) {
        float wv = w1[(size_t)c * 1024 + t];
        s1 += g1[c] * wv;
        s2 += g2[c] * wv;
    }
    h1ab[t]        = fmaxf(s1, 0.f);
    h1ab[1024 + t] = fmaxf(s2, 0.f);
}

// ---------------------------------------------------------------------------
// K6b: h2 = relu(h1 @ w2 + b2), split-K (16 K-groups of 64), LDS tree reduce.
// ---------------------------------------------------------------------------
__global__ __launch_bounds__(256) void k_mlp2(
    const float* __restrict__ h1ab, const float* __restrict__ w2,
    const float* __restrict__ b2, float* __restrict__ h2ab)
{
    __shared__ float h1s[1024];
    __shared__ float sm[256];
    const int v   = blockIdx.x & 1;
    const int ob  = blockIdx.x >> 1;      // 0..63
    const int tid = threadIdx.x;
    const int o   = tid & 15, g = tid >> 4;
    for (int i = tid; i < 1024; i += 256) h1s[i] = h1ab[v * 1024 + i];
    __syncthreads();
    const float* wp = w2 + (size_t)(g * 64) * 1024 + ob * 16 + o;
    float acc = 0.f;
    #pragma unroll 8
    for (int k = 0; k < 64; ++k)
        acc += h1s[g * 64 + k] * wp[(size_t)k * 1024];
    sm[tid] = acc;
    __syncthreads();
    if (tid < 16) {
        float s = b2[ob * 16 + tid];
        #pragma unroll
        for (int g2 = 0; g2 < 16; ++g2) s += sm[g2 * 16 + tid];
        h2ab[v * 1024 + ob * 16 + tid] = fmaxf(s, 0.f);
    }
}

// ---------------------------------------------------------------------------
// K6c: out = relu(h2a@w3+b3) + 0.002*relu(h2b@w3+b3), split-K, both variants.
// ---------------------------------------------------------------------------
__global__ __launch_bounds__(512) void k_mlp3(
    const float* __restrict__ h2ab, const float* __restrict__ w3,
    const float* __restrict__ b3, float* __restrict__ out)
{
    __shared__ float sm[512];
    const int tid = threadIdx.x;
    const int v   = tid >> 8;
    const int g   = (tid >> 4) & 15;
    const int o   = tid & 15;
    const int ob  = blockIdx.x;           // 16 blocks x 16 outputs
    const float* hp = h2ab + v * 1024 + g * 64;
    const float* wp = w3 + (size_t)(g * 64) * 256 + ob * 16 + o;
    float acc = 0.f;
    #pragma unroll 8
    for (int k = 0; k < 64; ++k)
        acc += hp[k] * wp[(size_t)k * 256];
    sm[tid] = acc;
    __syncthreads();
    if (tid < 16) {
        float pa = b3[ob * 16 + tid], pb = pa;
        #pragma unroll
        for (int g2 = 0; g2 < 16; ++g2) {
            pa += sm[g2 * 16 + tid];
            pb += sm[256 + g2 * 16 + tid];
        }
        out[ob * 16 + tid] = fmaxf(pa, 0.f) + 0.002f * fmaxf(pb, 0.f);
    }
}

// ---------------------------------------------------------------------------
extern "C" void kernel_launch(void* const* d_in, const int* in_sizes, int n_in,
                              void* d_out, int out_size, void* d_ws, size_t ws_size,
                              hipStream_t stream)
{
    const float* x   = (const float*)d_in[0];
    const float* A   = (const float*)d_in[1];
    const float* gw1 = (const float*)d_in[2];
    const float* gb1 = (const float*)d_in[3];
    const float* gw2 = (const float*)d_in[4];
    const float* gb2 = (const float*)d_in[5];
    const float* gw3 = (const float*)d_in[6];
    const float* gb3 = (const float*)d_in[7];
    const float* aw1 = (const float*)d_in[8];
    const float* ab1 = (const float*)d_in[9];
    const float* aw2 = (const float*)d_in[10];
    const float* ab2 = (const float*)d_in[11];
    const float* aw3 = (const float*)d_in[12];
    const float* ab3 = (const float*)d_in[13];
    float* out = (float*)d_out;

    char* ws = (char*)d_ws;
    float* scores   = (float*)(ws + 0);            // 16384 f32
    float* attn     = (float*)(ws + 65536);        // 16384 f32
    float* red      = (float*)(ws + 131072);       // 2 f32 (max, sumexp)
    float* gc       = (float*)(ws + 131328);       // 32 f32
    float* h1ab     = (float*)(ws + 131584);       // 2048 f32
    float* h2ab     = (float*)(ws + 139776);       // 2048 f32
    float* partials = (float*)(ws + 163840);       // 16384 f32 (ends 229376)
    float* part2    = (float*)(ws + 229376);       // 2048 f32 probe sink
    unsigned short* wfT = (unsigned short*)(ws + 262144);  // 32*16384 bf16 = 1 MB

    k_zero       <<<1,    32,   0, stream>>>(gc);
    k_attn_scores<<<N_NODES/32, 256, 0, stream>>>(x, aw1, ab1, aw2, ab2, aw3, ab3, scores);
    k_softmax_red<<<1,    1024, 0, stream>>>(scores, red);
    k_attn_wf    <<<N_NODES/256, 256, 0, stream>>>(scores, red, x, attn, wfT, gc);
    k_context    <<<16384, 256, 0, stream>>>(A, wfT, x, attn, partials);
    k_readprobe  <<<2048, 256,  0, stream>>>(A, part2);   // DIAGNOSTIC: 536MB linear read
    k_mlp1       <<<1,    1024, 0, stream>>>(gc, partials, gw1, gb1, h1ab);
    k_mlp2       <<<128,  256,  0, stream>>>(h1ab, gw2, gb2, h2ab);
    k_mlp3       <<<16,   512,  0, stream>>>(h2ab, gw3, gb3, out);
}

// Round 15
// 297.004 us; speedup vs baseline: 1.2808x; 1.2808x over previous
//
#include <hip/hip_runtime.h>
#include <hip/hip_bf16.h>
#include <math.h>

#define N_NODES 16384
#define C_IN 32

typedef __attribute__((ext_vector_type(8))) short short8;
typedef __attribute__((ext_vector_type(4))) short s16x4;
typedef __attribute__((ext_vector_type(4))) float f32x4;
typedef __attribute__((ext_vector_type(4))) float f4v;

__device__ __forceinline__ unsigned short f2bf(float f) {
    unsigned u = __float_as_uint(f);
    u = u + 0x7fffu + ((u >> 16) & 1u);   // RNE to bf16
    return (unsigned short)(u >> 16);
}

// ---------------------------------------------------------------------------
// K0: zero gc[32]
// ---------------------------------------------------------------------------
__global__ void k_zero(float* __restrict__ p) {
    p[threadIdx.x] = 0.f;
}

// ---------------------------------------------------------------------------
// K1 v2: attention scores, 32 nodes per 256-thread block (512 blocks).
// ---------------------------------------------------------------------------
__global__ __launch_bounds__(256) void k_attn_scores(
    const float* __restrict__ x,
    const float* __restrict__ aw1, const float* __restrict__ ab1,
    const float* __restrict__ aw2, const float* __restrict__ ab2,
    const float* __restrict__ aw3, const float* __restrict__ ab3,
    float* __restrict__ scores)
{
    __shared__ float w1s[4096];   // [32][128]
    __shared__ float w2s[8192];   // [128][64]
    __shared__ float b1s[128];
    __shared__ float b2s[64];
    __shared__ float w3s[64];
    __shared__ float xs[1024];    // 32 nodes x 32 ch
    __shared__ float h1s[4096];   // 32 nodes x 128

    const int tid = threadIdx.x;
    for (int i = tid; i < 4096; i += 256) w1s[i] = aw1[i];
    for (int i = tid; i < 8192; i += 256) w2s[i] = aw2[i];
    if (tid < 128) b1s[tid] = ab1[tid];
    if (tid < 64)  { b2s[tid] = ab2[tid]; w3s[tid] = aw3[tid]; }
    #pragma unroll
    for (int i = 0; i < 4; ++i)
        xs[tid + 256 * i] = x[(size_t)blockIdx.x * 1024 + tid + 256 * i];
    __syncthreads();

    const int g   = tid >> 5;   // lane-group 0..7 -> nodes g*4..g*4+3
    const int t31 = tid & 31;

    float a0[4], a1[4], a2[4], a3[4];
    #pragma unroll
    for (int nn = 0; nn < 4; ++nn) {
        a0[nn] = b1s[t31*4+0]; a1[nn] = b1s[t31*4+1];
        a2[nn] = b1s[t31*4+2]; a3[nn] = b1s[t31*4+3];
    }
    #pragma unroll
    for (int c = 0; c < 32; ++c) {
        float4 w = *(const float4*)&w1s[c*128 + t31*4];
        #pragma unroll
        for (int nn = 0; nn < 4; ++nn) {
            float xv = xs[(g*4 + nn)*32 + c];
            a0[nn] += xv * w.x; a1[nn] += xv * w.y;
            a2[nn] += xv * w.z; a3[nn] += xv * w.w;
        }
    }
    #pragma unroll
    for (int nn = 0; nn < 4; ++nn)
        *(float4*)&h1s[(g*4 + nn)*128 + t31*4] =
            make_float4(fmaxf(a0[nn],0.f), fmaxf(a1[nn],0.f),
                        fmaxf(a2[nn],0.f), fmaxf(a3[nn],0.f));
    __syncthreads();

    float c0[4], c1[4];
    #pragma unroll
    for (int nn = 0; nn < 4; ++nn) { c0[nn] = b2s[t31*2]; c1[nn] = b2s[t31*2+1]; }
    #pragma unroll 4
    for (int o = 0; o < 128; ++o) {
        float2 w = *(const float2*)&w2s[o*64 + t31*2];
        #pragma unroll
        for (int nn = 0; nn < 4; ++nn) {
            float hv = h1s[(g*4 + nn)*128 + o];
            c0[nn] += hv * w.x;
            c1[nn] += hv * w.y;
        }
    }
    #pragma unroll
    for (int nn = 0; nn < 4; ++nn) {
        float s = fmaxf(c0[nn], 0.f) * w3s[t31*2] + fmaxf(c1[nn], 0.f) * w3s[t31*2 + 1];
        s += __shfl_xor(s, 1);  s += __shfl_xor(s, 2);  s += __shfl_xor(s, 4);
        s += __shfl_xor(s, 8);  s += __shfl_xor(s, 16);
        if (t31 == 0) scores[(size_t)blockIdx.x * 32 + g*4 + nn] = s + ab3[0];
    }
}

// ---------------------------------------------------------------------------
// K2: softmax max + sum(exp) over 16384 scores, single block
// ---------------------------------------------------------------------------
__global__ __launch_bounds__(1024) void k_softmax_red(
    const float* __restrict__ scores, float* __restrict__ red)
{
    __shared__ float sm[1024];
    const int tid = threadIdx.x;
    float m = -3.4e38f;
    for (int i = tid; i < N_NODES; i += 1024) m = fmaxf(m, scores[i]);
    sm[tid] = m; __syncthreads();
    for (int s = 512; s > 0; s >>= 1) {
        if (tid < s) sm[tid] = fmaxf(sm[tid], sm[tid + s]);
        __syncthreads();
    }
    m = sm[0];
    __syncthreads();
    float acc = 0.f;
    for (int i = tid; i < N_NODES; i += 1024) acc += expf(scores[i] - m);
    sm[tid] = acc; __syncthreads();
    for (int s = 512; s > 0; s >>= 1) {
        if (tid < s) sm[tid] += sm[tid + s];
        __syncthreads();
    }
    if (tid == 0) { red[0] = m; red[1] = sm[0]; }
}

// ---------------------------------------------------------------------------
// K3: attn = softmax(scores); wfT(bf16, transposed [32][16384]); gc = sum(wf)
// ---------------------------------------------------------------------------
__global__ __launch_bounds__(256) void k_attn_wf(
    const float* __restrict__ scores, const float* __restrict__ red,
    const float* __restrict__ x, float* __restrict__ attn,
    unsigned short* __restrict__ wfT, float* __restrict__ gc)
{
    const int n = blockIdx.x * 256 + threadIdx.x;
    const float m = red[0], s = red[1];
    const float a = expf(scores[n] - m) / s;
    attn[n] = a;

    float wv[32];
    const float4* xr = (const float4*)(x + (size_t)n * 32);
    #pragma unroll
    for (int q = 0; q < 8; ++q) {
        float4 v = xr[q];
        wv[q*4+0] = v.x * a; wv[q*4+1] = v.y * a;
        wv[q*4+2] = v.z * a; wv[q*4+3] = v.w * a;
    }
    #pragma unroll
    for (int c = 0; c < 32; ++c)
        wfT[(size_t)c * N_NODES + n] = f2bf(wv[c]);   // coalesced per c

    const int lane = threadIdx.x & 63;
    #pragma unroll
    for (int c = 0; c < 32; ++c) {
        float v = wv[c];
        v += __shfl_xor(v, 1);  v += __shfl_xor(v, 2);  v += __shfl_xor(v, 4);
        v += __shfl_xor(v, 8);  v += __shfl_xor(v, 16); v += __shfl_xor(v, 32);
        if (lane == 0) atomicAdd(&gc[c], v);
    }
}

// ---------------------------------------------------------------------------
// K5 v8: identical to v7 EXCEPT the A loads are PLAIN (not nontemporal).
// Single-variable experiment: r14's probe (plain loads) measured 5.2-5.5
// TB/s read ceiling; v7 with NT loads runs 4.47. If NT's cache-bypass is
// the limiter (unaggregated 64B HBM requests), plain loads close the gap.
// ---------------------------------------------------------------------------
__global__ __launch_bounds__(256, 3) void k_context(
    const float* __restrict__ A, const unsigned short* __restrict__ wfT,
    const float* __restrict__ x, const float* __restrict__ attn,
    float* __restrict__ partials)
{
    __shared__ unsigned short sB_u[32 * 256];    // 16 KB, XOR-swizzled
    __shared__ short sA[4][16 * 256];            // 32 KB: per-wave 16 rows x 256
    __shared__ float sRed[4];

    const int tid   = threadIdx.x;
    const int wid   = tid >> 6, lane = tid & 63;
    const int js    = blockIdx.x & 63;    // 64 col-splits of 256  (LOW bits)
    const int rb    = blockIdx.x >> 6;    // 256 row-blocks of 64 rows
    const int i0    = rb * 64 + wid * 16;
    const int gcol0 = js * 256;

    const int q   = lane >> 4;
    const int r16 = lane & 15;
    char* wbase = (char*)sA[wid];

    // ---- issue A loads FIRST: 16 instructions, each one full row = 1KB ----
    f4v av[16];
    #pragma unroll
    for (int r = 0; r < 16; ++r)
        av[r] = *(const f4v*)(A + (size_t)(i0 + r) * N_NODES + gcol0 + lane * 4);

    // ---- stage B slice (L2-resident wfT): 32 rows x 512B, swizzled ----
    {
        const int row = tid >> 3;                 // 0..31
        const unsigned short* gB = wfT + (size_t)row * N_NODES + gcol0;
        char* lB = (char*)sB_u + row * 512;
        #pragma unroll
        for (int c = 0; c < 4; ++c) {
            const int chunk = (tid & 7) + 8 * c;  // 0..31, 16B each
            short8 v = *(const short8*)(gB + chunk * 8);
            *(short8*)(lB + ((chunk * 16) ^ ((row & 7) << 4))) = v;
        }
    }
    __syncthreads();   // B visible to all waves (also implies vmcnt drain of A)

    // ---- cvt + write A rows into wave-private LDS (8B/lane, swizzled) ----
    #pragma unroll
    for (int r = 0; r < 16; ++r) {
        s16x4 w;
        w[0] = (short)f2bf(av[r][0]); w[1] = (short)f2bf(av[r][1]);
        w[2] = (short)f2bf(av[r][2]); w[3] = (short)f2bf(av[r][3]);
        *(s16x4*)(wbase + r * 512 + ((lane * 8) ^ ((r & 7) << 4))) = w;
    }

    // ---- MFMA: 8 k-slices x 2 channel-halves (wave-private A, shared B) ----
    f32x4 acc0 = {0.f, 0.f, 0.f, 0.f};
    f32x4 acc1 = {0.f, 0.f, 0.f, 0.f};
    const int swzA = (r16 & 7) << 4;
    const char* sBb = (const char*)sB_u;
    #pragma unroll
    for (int kk = 0; kk < 8; ++kk) {
        const int fo = kk * 64 + q * 16;
        short8 afr = *(const short8*)(wbase + r16 * 512 + (fo ^ swzA));
        short8 b0  = *(const short8*)(sBb + r16 * 512        + (fo ^ swzA));
        short8 b1  = *(const short8*)(sBb + (r16 + 16) * 512 + (fo ^ swzA));
        acc0 = __builtin_amdgcn_mfma_f32_16x16x32_bf16(afr, b0, acc0, 0, 0, 0);
        acc1 = __builtin_amdgcn_mfma_f32_16x16x32_bf16(afr, b1, acc1, 0, 0, 0);
    }

    // ---- epilogue: D[row=q*4+r, col=r16]; dot with wf = x*attn, reduce ----
    float partial = 0.f;
    #pragma unroll
    for (int r = 0; r < 4; ++r) {
        const int i = i0 + q * 4 + r;
        const float a = attn[i];
        partial += acc0[r] * (x[(size_t)i * 32 + r16]      * a);
        partial += acc1[r] * (x[(size_t)i * 32 + 16 + r16] * a);
    }
    partial += __shfl_xor(partial, 1);  partial += __shfl_xor(partial, 2);
    partial += __shfl_xor(partial, 4);  partial += __shfl_xor(partial, 8);
    partial += __shfl_xor(partial, 16); partial += __shfl_xor(partial, 32);
    if (lane == 0) sRed[wid] = partial;
    __syncthreads();
    if (tid == 0) partials[blockIdx.x] = (sRed[0] + sRed[1]) + (sRed[2] + sRed[3]);
}

// ---------------------------------------------------------------------------
// K6a: reduce partials[16384] -> cs; h1 for gc and gc2 = gc + 0.001*(cs/N)
// ---------------------------------------------------------------------------
__global__ __launch_bounds__(1024) void k_mlp1(
    const float* __restrict__ gc, const float* __restrict__ partials,
    const float* __restrict__ w1, const float* __restrict__ b1,
    float* __restrict__ h1ab)
{
    __shared__ float sm[1024];
    __shared__ float g1[32], g2[32];
    const int t = threadIdx.x;
    float acc = 0.f;
    #pragma unroll
    for (int i = 0; i < 16; ++i) acc += partials[t + 1024 * i];
    sm[t] = acc; __syncthreads();
    for (int s = 512; s > 0; s >>= 1) {
        if (t < s) sm[t] += sm[t + s];
        __syncthreads();
    }
    if (t < 32) {
        float cs = sm[0] * (1.0f / 16384.0f);
        g1[t] = gc[t];
        g2[t] = gc[t] + 0.001f * cs;
    }
    __syncthreads();
    float s1 = b1[t], s2 = b1[t];
    #pragma unroll
    for (int c = 0; c < 32; ++c) {
        float wv = w1[(size_t)c * 1024 + t];
        s1 += g1[c] * wv;
        s2 += g2[c] * wv;
    }
    h1ab[t]        = fmaxf(s1, 0.f);
    h1ab[1024 + t] = fmaxf(s2, 0.f);
}

// ---------------------------------------------------------------------------
// K6b: h2 = relu(h1 @ w2 + b2), split-K (16 K-groups of 64), LDS tree reduce.
// ---------------------------------------------------------------------------
__global__ __launch_bounds__(256) void k_mlp2(
    const float* __restrict__ h1ab, const float* __restrict__ w2,
    const float* __restrict__ b2, float* __restrict__ h2ab)
{
    __shared__ float h1s[1024];
    __shared__ float sm[256];
    const int v   = blockIdx.x & 1;
    const int ob  = blockIdx.x >> 1;      // 0..63
    const int tid = threadIdx.x;
    const int o   = tid & 15, g = tid >> 4;
    for (int i = tid; i < 1024; i += 256) h1s[i] = h1ab[v * 1024 + i];
    __syncthreads();
    const float* wp = w2 + (size_t)(g * 64) * 1024 + ob * 16 + o;
    float acc = 0.f;
    #pragma unroll 8
    for (int k = 0; k < 64; ++k)
        acc += h1s[g * 64 + k] * wp[(size_t)k * 1024];
    sm[tid] = acc;
    __syncthreads();
    if (tid < 16) {
        float s = b2[ob * 16 + tid];
        #pragma unroll
        for (int g2 = 0; g2 < 16; ++g2) s += sm[g2 * 16 + tid];
        h2ab[v * 1024 + ob * 16 + tid] = fmaxf(s, 0.f);
    }
}

// ---------------------------------------------------------------------------
// K6c: out = relu(h2a@w3+b3) + 0.002*relu(h2b@w3+b3), split-K, both variants.
// ---------------------------------------------------------------------------
__global__ __launch_bounds__(512) void k_mlp3(
    const float* __restrict__ h2ab, const float* __restrict__ w3,
    const float* __restrict__ b3, float* __restrict__ out)
{
    __shared__ float sm[512];
    const int tid = threadIdx.x;
    const int v   = tid >> 8;
    const int g   = (tid >> 4) & 15;
    const int o   = tid & 15;
    const int ob  = blockIdx.x;           // 16 blocks x 16 outputs
    const float* hp = h2ab + v * 1024 + g * 64;
    const float* wp = w3 + (size_t)(g * 64) * 256 + ob * 16 + o;
    float acc = 0.f;
    #pragma unroll 8
    for (int k = 0; k < 64; ++k)
        acc += hp[k] * wp[(size_t)k * 256];
    sm[tid] = acc;
    __syncthreads();
    if (tid < 16) {
        float pa = b3[ob * 16 + tid], pb = pa;
        #pragma unroll
        for (int g2 = 0; g2 < 16; ++g2) {
            pa += sm[g2 * 16 + tid];
            pb += sm[256 + g2 * 16 + tid];
        }
        out[ob * 16 + tid] = fmaxf(pa, 0.f) + 0.002f * fmaxf(pb, 0.f);
    }
}

// ---------------------------------------------------------------------------
extern "C" void kernel_launch(void* const* d_in, const int* in_sizes, int n_in,
                              void* d_out, int out_size, void* d_ws, size_t ws_size,
                              hipStream_t stream)
{
    const float* x   = (const float*)d_in[0];
    const float* A   = (const float*)d_in[1];
    const float* gw1 = (const float*)d_in[2];
    const float* gb1 = (const float*)d_in[3];
    const float* gw2 = (const float*)d_in[4];
    const float* gb2 = (const float*)d_in[5];
    const float* gw3 = (const float*)d_in[6];
    const float* gb3 = (const float*)d_in[7];
    const float* aw1 = (const float*)d_in[8];
    const float* ab1 = (const float*)d_in[9];
    const float* aw2 = (const float*)d_in[10];
    const float* ab2 = (const float*)d_in[11];
    const float* aw3 = (const float*)d_in[12];
    const float* ab3 = (const float*)d_in[13];
    float* out = (float*)d_out;

    char* ws = (char*)d_ws;
    float* scores   = (float*)(ws + 0);            // 16384 f32
    float* attn     = (float*)(ws + 65536);        // 16384 f32
    float* red      = (float*)(ws + 131072);       // 2 f32 (max, sumexp)
    float* gc       = (float*)(ws + 131328);       // 32 f32
    float* h1ab     = (float*)(ws + 131584);       // 2048 f32
    float* h2ab     = (float*)(ws + 139776);       // 2048 f32
    float* partials = (float*)(ws + 163840);       // 16384 f32 (ends 229376)
    unsigned short* wfT = (unsigned short*)(ws + 262144);  // 32*16384 bf16 = 1 MB

    k_zero       <<<1,    32,   0, stream>>>(gc);
    k_attn_scores<<<N_NODES/32, 256, 0, stream>>>(x, aw1, ab1, aw2, ab2, aw3, ab3, scores);
    k_softmax_red<<<1,    1024, 0, stream>>>(scores, red);
    k_attn_wf    <<<N_NODES/256, 256, 0, stream>>>(scores, red, x, attn, wfT, gc);
    k_context    <<<16384, 256, 0, stream>>>(A, wfT, x, attn, partials);
    k_mlp1       <<<1,    1024, 0, stream>>>(gc, partials, gw1, gb1, h1ab);
    k_mlp2       <<<128,  256,  0, stream>>>(h1ab, gw2, gb2, h2ab);
    k_mlp3       <<<16,   512,  0, stream>>>(h2ab, gw3, gb3, out);
}

// Round 16
// 290.776 us; speedup vs baseline: 1.3082x; 1.0214x over previous
//
#include <hip/hip_runtime.h>
#include <hip/hip_bf16.h>
#include <math.h>

#define N_NODES 16384
#define C_IN 32

typedef __attribute__((ext_vector_type(8))) short short8;
typedef __attribute__((ext_vector_type(2))) short s16x2;
typedef __attribute__((ext_vector_type(4))) float f32x4;
typedef __attribute__((ext_vector_type(4))) float f4v;
typedef __attribute__((ext_vector_type(2))) float f2v;

__device__ __forceinline__ unsigned short f2bf(float f) {
    unsigned u = __float_as_uint(f);
    u = u + 0x7fffu + ((u >> 16) & 1u);   // RNE to bf16
    return (unsigned short)(u >> 16);
}

// ---------------------------------------------------------------------------
// K0: zero gc[32]
// ---------------------------------------------------------------------------
__global__ void k_zero(float* __restrict__ p) {
    p[threadIdx.x] = 0.f;
}

// ---------------------------------------------------------------------------
// K1 v2: attention scores, 32 nodes per 256-thread block (512 blocks).
// ---------------------------------------------------------------------------
__global__ __launch_bounds__(256) void k_attn_scores(
    const float* __restrict__ x,
    const float* __restrict__ aw1, const float* __restrict__ ab1,
    const float* __restrict__ aw2, const float* __restrict__ ab2,
    const float* __restrict__ aw3, const float* __restrict__ ab3,
    float* __restrict__ scores)
{
    __shared__ float w1s[4096];   // [32][128]
    __shared__ float w2s[8192];   // [128][64]
    __shared__ float b1s[128];
    __shared__ float b2s[64];
    __shared__ float w3s[64];
    __shared__ float xs[1024];    // 32 nodes x 32 ch
    __shared__ float h1s[4096];   // 32 nodes x 128

    const int tid = threadIdx.x;
    for (int i = tid; i < 4096; i += 256) w1s[i] = aw1[i];
    for (int i = tid; i < 8192; i += 256) w2s[i] = aw2[i];
    if (tid < 128) b1s[tid] = ab1[tid];
    if (tid < 64)  { b2s[tid] = ab2[tid]; w3s[tid] = aw3[tid]; }
    #pragma unroll
    for (int i = 0; i < 4; ++i)
        xs[tid + 256 * i] = x[(size_t)blockIdx.x * 1024 + tid + 256 * i];
    __syncthreads();

    const int g   = tid >> 5;   // lane-group 0..7 -> nodes g*4..g*4+3
    const int t31 = tid & 31;

    float a0[4], a1[4], a2[4], a3[4];
    #pragma unroll
    for (int nn = 0; nn < 4; ++nn) {
        a0[nn] = b1s[t31*4+0]; a1[nn] = b1s[t31*4+1];
        a2[nn] = b1s[t31*4+2]; a3[nn] = b1s[t31*4+3];
    }
    #pragma unroll
    for (int c = 0; c < 32; ++c) {
        float4 w = *(const float4*)&w1s[c*128 + t31*4];
        #pragma unroll
        for (int nn = 0; nn < 4; ++nn) {
            float xv = xs[(g*4 + nn)*32 + c];
            a0[nn] += xv * w.x; a1[nn] += xv * w.y;
            a2[nn] += xv * w.z; a3[nn] += xv * w.w;
        }
    }
    #pragma unroll
    for (int nn = 0; nn < 4; ++nn)
        *(float4*)&h1s[(g*4 + nn)*128 + t31*4] =
            make_float4(fmaxf(a0[nn],0.f), fmaxf(a1[nn],0.f),
                        fmaxf(a2[nn],0.f), fmaxf(a3[nn],0.f));
    __syncthreads();

    float c0[4], c1[4];
    #pragma unroll
    for (int nn = 0; nn < 4; ++nn) { c0[nn] = b2s[t31*2]; c1[nn] = b2s[t31*2+1]; }
    #pragma unroll 4
    for (int o = 0; o < 128; ++o) {
        float2 w = *(const float2*)&w2s[o*64 + t31*2];
        #pragma unroll
        for (int nn = 0; nn < 4; ++nn) {
            float hv = h1s[(g*4 + nn)*128 + o];
            c0[nn] += hv * w.x;
            c1[nn] += hv * w.y;
        }
    }
    #pragma unroll
    for (int nn = 0; nn < 4; ++nn) {
        float s = fmaxf(c0[nn], 0.f) * w3s[t31*2] + fmaxf(c1[nn], 0.f) * w3s[t31*2 + 1];
        s += __shfl_xor(s, 1);  s += __shfl_xor(s, 2);  s += __shfl_xor(s, 4);
        s += __shfl_xor(s, 8);  s += __shfl_xor(s, 16);
        if (t31 == 0) scores[(size_t)blockIdx.x * 32 + g*4 + nn] = s + ab3[0];
    }
}

// ---------------------------------------------------------------------------
// K2: softmax max + sum(exp) over 16384 scores, single block
// ---------------------------------------------------------------------------
__global__ __launch_bounds__(1024) void k_softmax_red(
    const float* __restrict__ scores, float* __restrict__ red)
{
    __shared__ float sm[1024];
    const int tid = threadIdx.x;
    float m = -3.4e38f;
    for (int i = tid; i < N_NODES; i += 1024) m = fmaxf(m, scores[i]);
    sm[tid] = m; __syncthreads();
    for (int s = 512; s > 0; s >>= 1) {
        if (tid < s) sm[tid] = fmaxf(sm[tid], sm[tid + s]);
        __syncthreads();
    }
    m = sm[0];
    __syncthreads();
    float acc = 0.f;
    for (int i = tid; i < N_NODES; i += 1024) acc += expf(scores[i] - m);
    sm[tid] = acc; __syncthreads();
    for (int s = 512; s > 0; s >>= 1) {
        if (tid < s) sm[tid] += sm[tid + s];
        __syncthreads();
    }
    if (tid == 0) { red[0] = m; red[1] = sm[0]; }
}

// ---------------------------------------------------------------------------
// K3: attn = softmax(scores); wfT(bf16, transposed [32][16384]); gc = sum(wf)
// ---------------------------------------------------------------------------
__global__ __launch_bounds__(256) void k_attn_wf(
    const float* __restrict__ scores, const float* __restrict__ red,
    const float* __restrict__ x, float* __restrict__ attn,
    unsigned short* __restrict__ wfT, float* __restrict__ gc)
{
    const int n = blockIdx.x * 256 + threadIdx.x;
    const float m = red[0], s = red[1];
    const float a = expf(scores[n] - m) / s;
    attn[n] = a;

    float wv[32];
    const float4* xr = (const float4*)(x + (size_t)n * 32);
    #pragma unroll
    for (int q = 0; q < 8; ++q) {
        float4 v = xr[q];
        wv[q*4+0] = v.x * a; wv[q*4+1] = v.y * a;
        wv[q*4+2] = v.z * a; wv[q*4+3] = v.w * a;
    }
    #pragma unroll
    for (int c = 0; c < 32; ++c)
        wfT[(size_t)c * N_NODES + n] = f2bf(wv[c]);   // coalesced per c

    const int lane = threadIdx.x & 63;
    #pragma unroll
    for (int c = 0; c < 32; ++c) {
        float v = wv[c];
        v += __shfl_xor(v, 1);  v += __shfl_xor(v, 2);  v += __shfl_xor(v, 4);
        v += __shfl_xor(v, 8);  v += __shfl_xor(v, 16); v += __shfl_xor(v, 32);
        if (lane == 0) atomicAdd(&gc[c], v);
    }
}

// ---------------------------------------------------------------------------
// K5 v9: NT loads restored (plain regressed +17us: A evicts wfT from L2).
// Occupancy experiment: 128-col tiles -> sB 8KB + sA 16KB = 24KB LDS,
// __launch_bounds__(256,5) -> 5 blocks/CU (20 waves, was 12). Theory: the
// block lifecycle is issue->drain->compute (bursty in-flight profile); more
// co-resident blocks raise the HBM request duty cycle toward the probe's
// 5.2-5.5 TB/s. Grid = 256 rb x 128 js (js in LOW bits).
// ---------------------------------------------------------------------------
__global__ __launch_bounds__(256, 5) void k_context(
    const float* __restrict__ A, const unsigned short* __restrict__ wfT,
    const float* __restrict__ x, const float* __restrict__ attn,
    float* __restrict__ partials)
{
    __shared__ unsigned short sB_u[32 * 128];    // 8 KB, XOR-swizzled
    __shared__ short sA[4][16 * 128];            // 16 KB: per-wave 16 rows x 128
    __shared__ float sRed[4];

    const int tid   = threadIdx.x;
    const int wid   = tid >> 6, lane = tid & 63;
    const int js    = blockIdx.x & 127;   // 128 col-splits of 128 (LOW bits)
    const int rb    = blockIdx.x >> 7;    // 256 row-blocks of 64 rows
    const int i0    = rb * 64 + wid * 16;
    const int gcol0 = js * 128;

    const int q   = lane >> 4;
    const int r16 = lane & 15;
    char* wbase = (char*)sA[wid];

    // ---- issue A loads FIRST: 16 instructions, each one full row = 512B ----
    f2v av[16];
    #pragma unroll
    for (int r = 0; r < 16; ++r)
        av[r] = __builtin_nontemporal_load(
            (const f2v*)(A + (size_t)(i0 + r) * N_NODES + gcol0 + lane * 2));

    // ---- stage B slice (L2-resident wfT): 32 rows x 256B, swizzled ----
    {
        const int row = tid >> 3;                 // 0..31
        const unsigned short* gB = wfT + (size_t)row * N_NODES + gcol0;
        char* lB = (char*)sB_u + row * 256;
        #pragma unroll
        for (int c = 0; c < 2; ++c) {
            const int chunk = (tid & 7) * 2 + c;  // 0..15, 16B each
            short8 v = *(const short8*)(gB + chunk * 8);
            *(short8*)(lB + ((chunk * 16) ^ ((row & 7) << 4))) = v;
        }
    }
    __syncthreads();   // B visible to all waves (also implies vmcnt drain of A)

    // ---- cvt + write A rows into wave-private LDS (4B/lane, swizzled) ----
    #pragma unroll
    for (int r = 0; r < 16; ++r) {
        s16x2 w;
        w[0] = (short)f2bf(av[r][0]); w[1] = (short)f2bf(av[r][1]);
        *(s16x2*)(wbase + r * 256 + ((lane * 4) ^ ((r & 7) << 4))) = w;
    }

    // ---- MFMA: 4 k-slices x 2 channel-halves (wave-private A, shared B) ----
    f32x4 acc0 = {0.f, 0.f, 0.f, 0.f};
    f32x4 acc1 = {0.f, 0.f, 0.f, 0.f};
    const int swzA = (r16 & 7) << 4;
    const char* sBb = (const char*)sB_u;
    #pragma unroll
    for (int kk = 0; kk < 4; ++kk) {
        const int fo = kk * 64 + q * 16;
        short8 afr = *(const short8*)(wbase + r16 * 256 + (fo ^ swzA));
        short8 b0  = *(const short8*)(sBb + r16 * 256        + (fo ^ swzA));
        short8 b1  = *(const short8*)(sBb + (r16 + 16) * 256 + (fo ^ swzA));
        // (r16+16)&7 == r16&7 (16 = 0 mod 8) -> same swizzle key for both B rows
        acc0 = __builtin_amdgcn_mfma_f32_16x16x32_bf16(afr, b0, acc0, 0, 0, 0);
        acc1 = __builtin_amdgcn_mfma_f32_16x16x32_bf16(afr, b1, acc1, 0, 0, 0);
    }

    // ---- epilogue: D[row=q*4+r, col=r16]; dot with wf = x*attn, reduce ----
    float partial = 0.f;
    #pragma unroll
    for (int r = 0; r < 4; ++r) {
        const int i = i0 + q * 4 + r;
        const float a = attn[i];
        partial += acc0[r] * (x[(size_t)i * 32 + r16]      * a);
        partial += acc1[r] * (x[(size_t)i * 32 + 16 + r16] * a);
    }
    partial += __shfl_xor(partial, 1);  partial += __shfl_xor(partial, 2);
    partial += __shfl_xor(partial, 4);  partial += __shfl_xor(partial, 8);
    partial += __shfl_xor(partial, 16); partial += __shfl_xor(partial, 32);
    if (lane == 0) sRed[wid] = partial;
    __syncthreads();
    if (tid == 0) partials[blockIdx.x] = (sRed[0] + sRed[1]) + (sRed[2] + sRed[3]);
}

// ---------------------------------------------------------------------------
// K6a: reduce partials[32768] -> cs; h1 for gc and gc2 = gc + 0.001*(cs/N)
// ---------------------------------------------------------------------------
__global__ __launch_bounds__(1024) void k_mlp1(
    const float* __restrict__ gc, const float* __restrict__ partials,
    const float* __restrict__ w1, const float* __restrict__ b1,
    float* __restrict__ h1ab)
{
    __shared__ float sm[1024];
    __shared__ float g1[32], g2[32];
    const int t = threadIdx.x;
    float acc = 0.f;
    #pragma unroll 8
    for (int i = 0; i < 32; ++i) acc += partials[t + 1024 * i];
    sm[t] = acc; __syncthreads();
    for (int s = 512; s > 0; s >>= 1) {
        if (t < s) sm[t] += sm[t + s];
        __syncthreads();
    }
    if (t < 32) {
        float cs = sm[0] * (1.0f / 16384.0f);
        g1[t] = gc[t];
        g2[t] = gc[t] + 0.001f * cs;
    }
    __syncthreads();
    float s1 = b1[t], s2 = b1[t];
    #pragma unroll
    for (int c = 0; c < 32; ++c) {
        float wv = w1[(size_t)c * 1024 + t];
        s1 += g1[c] * wv;
        s2 += g2[c] * wv;
    }
    h1ab[t]        = fmaxf(s1, 0.f);
    h1ab[1024 + t] = fmaxf(s2, 0.f);
}

// ---------------------------------------------------------------------------
// K6b: h2 = relu(h1 @ w2 + b2), split-K (16 K-groups of 64), LDS tree reduce.
// ---------------------------------------------------------------------------
__global__ __launch_bounds__(256) void k_mlp2(
    const float* __restrict__ h1ab, const float* __restrict__ w2,
    const float* __restrict__ b2, float* __restrict__ h2ab)
{
    __shared__ float h1s[1024];
    __shared__ float sm[256];
    const int v   = blockIdx.x & 1;
    const int ob  = blockIdx.x >> 1;      // 0..63
    const int tid = threadIdx.x;
    const int o   = tid & 15, g = tid >> 4;
    for (int i = tid; i < 1024; i += 256) h1s[i] = h1ab[v * 1024 + i];
    __syncthreads();
    const float* wp = w2 + (size_t)(g * 64) * 1024 + ob * 16 + o;
    float acc = 0.f;
    #pragma unroll 8
    for (int k = 0; k < 64; ++k)
        acc += h1s[g * 64 + k] * wp[(size_t)k * 1024];
    sm[tid] = acc;
    __syncthreads();
    if (tid < 16) {
        float s = b2[ob * 16 + tid];
        #pragma unroll
        for (int g2 = 0; g2 < 16; ++g2) s += sm[g2 * 16 + tid];
        h2ab[v * 1024 + ob * 16 + tid] = fmaxf(s, 0.f);
    }
}

// ---------------------------------------------------------------------------
// K6c: out = relu(h2a@w3+b3) + 0.002*relu(h2b@w3+b3), split-K, both variants.
// ---------------------------------------------------------------------------
__global__ __launch_bounds__(512) void k_mlp3(
    const float* __restrict__ h2ab, const float* __restrict__ w3,
    const float* __restrict__ b3, float* __restrict__ out)
{
    __shared__ float sm[512];
    const int tid = threadIdx.x;
    const int v   = tid >> 8;
    const int g   = (tid >> 4) & 15;
    const int o   = tid & 15;
    const int ob  = blockIdx.x;           // 16 blocks x 16 outputs
    const float* hp = h2ab + v * 1024 + g * 64;
    const float* wp = w3 + (size_t)(g * 64) * 256 + ob * 16 + o;
    float acc = 0.f;
    #pragma unroll 8
    for (int k = 0; k < 64; ++k)
        acc += hp[k] * wp[(size_t)k * 256];
    sm[tid] = acc;
    __syncthreads();
    if (tid < 16) {
        float pa = b3[ob * 16 + tid], pb = pa;
        #pragma unroll
        for (int g2 = 0; g2 < 16; ++g2) {
            pa += sm[g2 * 16 + tid];
            pb += sm[256 + g2 * 16 + tid];
        }
        out[ob * 16 + tid] = fmaxf(pa, 0.f) + 0.002f * fmaxf(pb, 0.f);
    }
}

// ---------------------------------------------------------------------------
extern "C" void kernel_launch(void* const* d_in, const int* in_sizes, int n_in,
                              void* d_out, int out_size, void* d_ws, size_t ws_size,
                              hipStream_t stream)
{
    const float* x   = (const float*)d_in[0];
    const float* A   = (const float*)d_in[1];
    const float* gw1 = (const float*)d_in[2];
    const float* gb1 = (const float*)d_in[3];
    const float* gw2 = (const float*)d_in[4];
    const float* gb2 = (const float*)d_in[5];
    const float* gw3 = (const float*)d_in[6];
    const float* gb3 = (const float*)d_in[7];
    const float* aw1 = (const float*)d_in[8];
    const float* ab1 = (const float*)d_in[9];
    const float* aw2 = (const float*)d_in[10];
    const float* ab2 = (const float*)d_in[11];
    const float* aw3 = (const float*)d_in[12];
    const float* ab3 = (const float*)d_in[13];
    float* out = (float*)d_out;

    char* ws = (char*)d_ws;
    float* scores   = (float*)(ws + 0);            // 16384 f32
    float* attn     = (float*)(ws + 65536);        // 16384 f32
    float* red      = (float*)(ws + 131072);       // 2 f32 (max, sumexp)
    float* gc       = (float*)(ws + 131328);       // 32 f32
    float* h1ab     = (float*)(ws + 131584);       // 2048 f32
    float* h2ab     = (float*)(ws + 139776);       // 2048 f32
    float* partials = (float*)(ws + 163840);       // 32768 f32 (ends 294912)
    unsigned short* wfT = (unsigned short*)(ws + 327680);  // 32*16384 bf16 = 1 MB

    k_zero       <<<1,    32,   0, stream>>>(gc);
    k_attn_scores<<<N_NODES/32, 256, 0, stream>>>(x, aw1, ab1, aw2, ab2, aw3, ab3, scores);
    k_softmax_red<<<1,    1024, 0, stream>>>(scores, red);
    k_attn_wf    <<<N_NODES/256, 256, 0, stream>>>(scores, red, x, attn, wfT, gc);
    k_context    <<<32768, 256, 0, stream>>>(A, wfT, x, attn, partials);
    k_mlp1       <<<1,    1024, 0, stream>>>(gc, partials, gw1, gb1, h1ab);
    k_mlp2       <<<128,  256,  0, stream>>>(h1ab, gw2, gb2, h2ab);
    k_mlp3       <<<16,   512,  0, stream>>>(h2ab, gw3, gb3, out);
}

// Round 17
// 284.370 us; speedup vs baseline: 1.3377x; 1.0225x over previous
//
#include <hip/hip_runtime.h>
#include <hip/hip_bf16.h>
#include <math.h>

#define N_NODES 16384
#define C_IN 32

typedef __attribute__((ext_vector_type(8))) short short8;
typedef __attribute__((ext_vector_type(4))) short s16x4;
typedef __attribute__((ext_vector_type(4))) float f32x4;
typedef __attribute__((ext_vector_type(4))) float f4v;

__device__ __forceinline__ unsigned short f2bf(float f) {
    unsigned u = __float_as_uint(f);
    u = u + 0x7fffu + ((u >> 16) & 1u);   // RNE to bf16
    return (unsigned short)(u >> 16);
}

// ---------------------------------------------------------------------------
// K0: zero gc[32]
// ---------------------------------------------------------------------------
__global__ void k_zero(float* __restrict__ p) {
    p[threadIdx.x] = 0.f;
}

// ---------------------------------------------------------------------------
// K1 v2: attention scores, 32 nodes per 256-thread block (512 blocks).
// ---------------------------------------------------------------------------
__global__ __launch_bounds__(256) void k_attn_scores(
    const float* __restrict__ x,
    const float* __restrict__ aw1, const float* __restrict__ ab1,
    const float* __restrict__ aw2, const float* __restrict__ ab2,
    const float* __restrict__ aw3, const float* __restrict__ ab3,
    float* __restrict__ scores)
{
    __shared__ float w1s[4096];   // [32][128]
    __shared__ float w2s[8192];   // [128][64]
    __shared__ float b1s[128];
    __shared__ float b2s[64];
    __shared__ float w3s[64];
    __shared__ float xs[1024];    // 32 nodes x 32 ch
    __shared__ float h1s[4096];   // 32 nodes x 128

    const int tid = threadIdx.x;
    for (int i = tid; i < 4096; i += 256) w1s[i] = aw1[i];
    for (int i = tid; i < 8192; i += 256) w2s[i] = aw2[i];
    if (tid < 128) b1s[tid] = ab1[tid];
    if (tid < 64)  { b2s[tid] = ab2[tid]; w3s[tid] = aw3[tid]; }
    #pragma unroll
    for (int i = 0; i < 4; ++i)
        xs[tid + 256 * i] = x[(size_t)blockIdx.x * 1024 + tid + 256 * i];
    __syncthreads();

    const int g   = tid >> 5;   // lane-group 0..7 -> nodes g*4..g*4+3
    const int t31 = tid & 31;

    float a0[4], a1[4], a2[4], a3[4];
    #pragma unroll
    for (int nn = 0; nn < 4; ++nn) {
        a0[nn] = b1s[t31*4+0]; a1[nn] = b1s[t31*4+1];
        a2[nn] = b1s[t31*4+2]; a3[nn] = b1s[t31*4+3];
    }
    #pragma unroll
    for (int c = 0; c < 32; ++c) {
        float4 w = *(const float4*)&w1s[c*128 + t31*4];
        #pragma unroll
        for (int nn = 0; nn < 4; ++nn) {
            float xv = xs[(g*4 + nn)*32 + c];
            a0[nn] += xv * w.x; a1[nn] += xv * w.y;
            a2[nn] += xv * w.z; a3[nn] += xv * w.w;
        }
    }
    #pragma unroll
    for (int nn = 0; nn < 4; ++nn)
        *(float4*)&h1s[(g*4 + nn)*128 + t31*4] =
            make_float4(fmaxf(a0[nn],0.f), fmaxf(a1[nn],0.f),
                        fmaxf(a2[nn],0.f), fmaxf(a3[nn],0.f));
    __syncthreads();

    float c0[4], c1[4];
    #pragma unroll
    for (int nn = 0; nn < 4; ++nn) { c0[nn] = b2s[t31*2]; c1[nn] = b2s[t31*2+1]; }
    #pragma unroll 4
    for (int o = 0; o < 128; ++o) {
        float2 w = *(const float2*)&w2s[o*64 + t31*2];
        #pragma unroll
        for (int nn = 0; nn < 4; ++nn) {
            float hv = h1s[(g*4 + nn)*128 + o];
            c0[nn] += hv * w.x;
            c1[nn] += hv * w.y;
        }
    }
    #pragma unroll
    for (int nn = 0; nn < 4; ++nn) {
        float s = fmaxf(c0[nn], 0.f) * w3s[t31*2] + fmaxf(c1[nn], 0.f) * w3s[t31*2 + 1];
        s += __shfl_xor(s, 1);  s += __shfl_xor(s, 2);  s += __shfl_xor(s, 4);
        s += __shfl_xor(s, 8);  s += __shfl_xor(s, 16);
        if (t31 == 0) scores[(size_t)blockIdx.x * 32 + g*4 + nn] = s + ab3[0];
    }
}

// ---------------------------------------------------------------------------
// K2: softmax max + sum(exp) over 16384 scores, single block
// ---------------------------------------------------------------------------
__global__ __launch_bounds__(1024) void k_softmax_red(
    const float* __restrict__ scores, float* __restrict__ red)
{
    __shared__ float sm[1024];
    const int tid = threadIdx.x;
    float m = -3.4e38f;
    for (int i = tid; i < N_NODES; i += 1024) m = fmaxf(m, scores[i]);
    sm[tid] = m; __syncthreads();
    for (int s = 512; s > 0; s >>= 1) {
        if (tid < s) sm[tid] = fmaxf(sm[tid], sm[tid + s]);
        __syncthreads();
    }
    m = sm[0];
    __syncthreads();
    float acc = 0.f;
    for (int i = tid; i < N_NODES; i += 1024) acc += expf(scores[i] - m);
    sm[tid] = acc; __syncthreads();
    for (int s = 512; s > 0; s >>= 1) {
        if (tid < s) sm[tid] += sm[tid + s];
        __syncthreads();
    }
    if (tid == 0) { red[0] = m; red[1] = sm[0]; }
}

// ---------------------------------------------------------------------------
// K3: attn = softmax(scores); wfT(bf16, transposed [32][16384]); gc = sum(wf)
// ---------------------------------------------------------------------------
__global__ __launch_bounds__(256) void k_attn_wf(
    const float* __restrict__ scores, const float* __restrict__ red,
    const float* __restrict__ x, float* __restrict__ attn,
    unsigned short* __restrict__ wfT, float* __restrict__ gc)
{
    const int n = blockIdx.x * 256 + threadIdx.x;
    const float m = red[0], s = red[1];
    const float a = expf(scores[n] - m) / s;
    attn[n] = a;

    float wv[32];
    const float4* xr = (const float4*)(x + (size_t)n * 32);
    #pragma unroll
    for (int q = 0; q < 8; ++q) {
        float4 v = xr[q];
        wv[q*4+0] = v.x * a; wv[q*4+1] = v.y * a;
        wv[q*4+2] = v.z * a; wv[q*4+3] = v.w * a;
    }
    #pragma unroll
    for (int c = 0; c < 32; ++c)
        wfT[(size_t)c * N_NODES + n] = f2bf(wv[c]);   // coalesced per c

    const int lane = threadIdx.x & 63;
    #pragma unroll
    for (int c = 0; c < 32; ++c) {
        float v = wv[c];
        v += __shfl_xor(v, 1);  v += __shfl_xor(v, 2);  v += __shfl_xor(v, 4);
        v += __shfl_xor(v, 8);  v += __shfl_xor(v, 16); v += __shfl_xor(v, 32);
        if (lane == 0) atomicAdd(&gc[c], v);
    }
}

// ---------------------------------------------------------------------------
// K5 v7 (best measured config): bulk + TLP, NT loads, 256-col tiles,
// js in LOW blockIdx bits. 4.45-4.5 TB/s on the A stream — the plateau
// of six structural variants; NT beats plain by ~17us (L2 wfT protection).
// ---------------------------------------------------------------------------
__global__ __launch_bounds__(256, 3) void k_context(
    const float* __restrict__ A, const unsigned short* __restrict__ wfT,
    const float* __restrict__ x, const float* __restrict__ attn,
    float* __restrict__ partials)
{
    __shared__ unsigned short sB_u[32 * 256];    // 16 KB, XOR-swizzled
    __shared__ short sA[4][16 * 256];            // 32 KB: per-wave 16 rows x 256
    __shared__ float sRed[4];

    const int tid   = threadIdx.x;
    const int wid   = tid >> 6, lane = tid & 63;
    const int js    = blockIdx.x & 63;    // 64 col-splits of 256  (LOW bits)
    const int rb    = blockIdx.x >> 6;    // 256 row-blocks of 64 rows
    const int i0    = rb * 64 + wid * 16;
    const int gcol0 = js * 256;

    const int q   = lane >> 4;
    const int r16 = lane & 15;
    char* wbase = (char*)sA[wid];

    // ---- issue A loads FIRST: 16 instructions, each one full row = 1KB ----
    f4v av[16];
    #pragma unroll
    for (int r = 0; r < 16; ++r)
        av[r] = __builtin_nontemporal_load(
            (const f4v*)(A + (size_t)(i0 + r) * N_NODES + gcol0 + lane * 4));

    // ---- stage B slice (L2-resident wfT): 32 rows x 512B, swizzled ----
    {
        const int row = tid >> 3;                 // 0..31
        const unsigned short* gB = wfT + (size_t)row * N_NODES + gcol0;
        char* lB = (char*)sB_u + row * 512;
        #pragma unroll
        for (int c = 0; c < 4; ++c) {
            const int chunk = (tid & 7) + 8 * c;  // 0..31, 16B each
            short8 v = *(const short8*)(gB + chunk * 8);
            *(short8*)(lB + ((chunk * 16) ^ ((row & 7) << 4))) = v;
        }
    }
    __syncthreads();   // B visible to all waves (also implies vmcnt drain of A)

    // ---- cvt + write A rows into wave-private LDS (8B/lane, swizzled) ----
    #pragma unroll
    for (int r = 0; r < 16; ++r) {
        s16x4 w;
        w[0] = (short)f2bf(av[r][0]); w[1] = (short)f2bf(av[r][1]);
        w[2] = (short)f2bf(av[r][2]); w[3] = (short)f2bf(av[r][3]);
        *(s16x4*)(wbase + r * 512 + ((lane * 8) ^ ((r & 7) << 4))) = w;
    }

    // ---- MFMA: 8 k-slices x 2 channel-halves (wave-private A, shared B) ----
    f32x4 acc0 = {0.f, 0.f, 0.f, 0.f};
    f32x4 acc1 = {0.f, 0.f, 0.f, 0.f};
    const int swzA = (r16 & 7) << 4;
    const char* sBb = (const char*)sB_u;
    #pragma unroll
    for (int kk = 0; kk < 8; ++kk) {
        const int fo = kk * 64 + q * 16;
        short8 afr = *(const short8*)(wbase + r16 * 512 + (fo ^ swzA));
        short8 b0  = *(const short8*)(sBb + r16 * 512        + (fo ^ swzA));
        short8 b1  = *(const short8*)(sBb + (r16 + 16) * 512 + (fo ^ swzA));
        // (r16+16)&7 == r16&7 (16 = 0 mod 8) -> same swizzle key for both B rows
        acc0 = __builtin_amdgcn_mfma_f32_16x16x32_bf16(afr, b0, acc0, 0, 0, 0);
        acc1 = __builtin_amdgcn_mfma_f32_16x16x32_bf16(afr, b1, acc1, 0, 0, 0);
    }

    // ---- epilogue: D[row=q*4+r, col=r16]; dot with wf = x*attn, reduce ----
    float partial = 0.f;
    #pragma unroll
    for (int r = 0; r < 4; ++r) {
        const int i = i0 + q * 4 + r;
        const float a = attn[i];
        partial += acc0[r] * (x[(size_t)i * 32 + r16]      * a);
        partial += acc1[r] * (x[(size_t)i * 32 + 16 + r16] * a);
    }
    partial += __shfl_xor(partial, 1);  partial += __shfl_xor(partial, 2);
    partial += __shfl_xor(partial, 4);  partial += __shfl_xor(partial, 8);
    partial += __shfl_xor(partial, 16); partial += __shfl_xor(partial, 32);
    if (lane == 0) sRed[wid] = partial;
    __syncthreads();
    if (tid == 0) partials[blockIdx.x] = (sRed[0] + sRed[1]) + (sRed[2] + sRed[3]);
}

// ---------------------------------------------------------------------------
// K6a: reduce partials[16384] -> cs; h1 for gc and gc2 = gc + 0.001*(cs/N)
// ---------------------------------------------------------------------------
__global__ __launch_bounds__(1024) void k_mlp1(
    const float* __restrict__ gc, const float* __restrict__ partials,
    const float* __restrict__ w1, const float* __restrict__ b1,
    float* __restrict__ h1ab)
{
    __shared__ float sm[1024];
    __shared__ float g1[32], g2[32];
    const int t = threadIdx.x;
    float acc = 0.f;
    #pragma unroll
    for (int i = 0; i < 16; ++i) acc += partials[t + 1024 * i];
    sm[t] = acc; __syncthreads();
    for (int s = 512; s > 0; s >>= 1) {
        if (t < s) sm[t] += sm[t + s];
        __syncthreads();
    }
    if (t < 32) {
        float cs = sm[0] * (1.0f / 16384.0f);
        g1[t] = gc[t];
        g2[t] = gc[t] + 0.001f * cs;
    }
    __syncthreads();
    float s1 = b1[t], s2 = b1[t];
    #pragma unroll
    for (int c = 0; c < 32; ++c) {
        float wv = w1[(size_t)c * 1024 + t];
        s1 += g1[c] * wv;
        s2 += g2[c] * wv;
    }
    h1ab[t]        = fmaxf(s1, 0.f);
    h1ab[1024 + t] = fmaxf(s2, 0.f);
}

// ---------------------------------------------------------------------------
// K6b: h2 = relu(h1 @ w2 + b2), split-K (16 K-groups of 64), LDS tree reduce.
// ---------------------------------------------------------------------------
__global__ __launch_bounds__(256) void k_mlp2(
    const float* __restrict__ h1ab, const float* __restrict__ w2,
    const float* __restrict__ b2, float* __restrict__ h2ab)
{
    __shared__ float h1s[1024];
    __shared__ float sm[256];
    const int v   = blockIdx.x & 1;
    const int ob  = blockIdx.x >> 1;      // 0..63
    const int tid = threadIdx.x;
    const int o   = tid & 15, g = tid >> 4;
    for (int i = tid; i < 1024; i += 256) h1s[i] = h1ab[v * 1024 + i];
    __syncthreads();
    const float* wp = w2 + (size_t)(g * 64) * 1024 + ob * 16 + o;
    float acc = 0.f;
    #pragma unroll 8
    for (int k = 0; k < 64; ++k)
        acc += h1s[g * 64 + k] * wp[(size_t)k * 1024];
    sm[tid] = acc;
    __syncthreads();
    if (tid < 16) {
        float s = b2[ob * 16 + tid];
        #pragma unroll
        for (int g2 = 0; g2 < 16; ++g2) s += sm[g2 * 16 + tid];
        h2ab[v * 1024 + ob * 16 + tid] = fmaxf(s, 0.f);
    }
}

// ---------------------------------------------------------------------------
// K6c: out = relu(h2a@w3+b3) + 0.002*relu(h2b@w3+b3), split-K, both variants.
// ---------------------------------------------------------------------------
__global__ __launch_bounds__(512) void k_mlp3(
    const float* __restrict__ h2ab, const float* __restrict__ w3,
    const float* __restrict__ b3, float* __restrict__ out)
{
    __shared__ float sm[512];
    const int tid = threadIdx.x;
    const int v   = tid >> 8;
    const int g   = (tid >> 4) & 15;
    const int o   = tid & 15;
    const int ob  = blockIdx.x;           // 16 blocks x 16 outputs
    const float* hp = h2ab + v * 1024 + g * 64;
    const float* wp = w3 + (size_t)(g * 64) * 256 + ob * 16 + o;
    float acc = 0.f;
    #pragma unroll 8
    for (int k = 0; k < 64; ++k)
        acc += hp[k] * wp[(size_t)k * 256];
    sm[tid] = acc;
    __syncthreads();
    if (tid < 16) {
        float pa = b3[ob * 16 + tid], pb = pa;
        #pragma unroll
        for (int g2 = 0; g2 < 16; ++g2) {
            pa += sm[g2 * 16 + tid];
            pb += sm[256 + g2 * 16 + tid];
        }
        out[ob * 16 + tid] = fmaxf(pa, 0.f) + 0.002f * fmaxf(pb, 0.f);
    }
}

// ---------------------------------------------------------------------------
extern "C" void kernel_launch(void* const* d_in, const int* in_sizes, int n_in,
                              void* d_out, int out_size, void* d_ws, size_t ws_size,
                              hipStream_t stream)
{
    const float* x   = (const float*)d_in[0];
    const float* A   = (const float*)d_in[1];
    const float* gw1 = (const float*)d_in[2];
    const float* gb1 = (const float*)d_in[3];
    const float* gw2 = (const float*)d_in[4];
    const float* gb2 = (const float*)d_in[5];
    const float* gw3 = (const float*)d_in[6];
    const float* gb3 = (const float*)d_in[7];
    const float* aw1 = (const float*)d_in[8];
    const float* ab1 = (const float*)d_in[9];
    const float* aw2 = (const float*)d_in[10];
    const float* ab2 = (const float*)d_in[11];
    const float* aw3 = (const float*)d_in[12];
    const float* ab3 = (const float*)d_in[13];
    float* out = (float*)d_out;

    char* ws = (char*)d_ws;
    float* scores   = (float*)(ws + 0);            // 16384 f32
    float* attn     = (float*)(ws + 65536);        // 16384 f32
    float* red      = (float*)(ws + 131072);       // 2 f32 (max, sumexp)
    float* gc       = (float*)(ws + 131328);       // 32 f32
    float* h1ab     = (float*)(ws + 131584);       // 2048 f32
    float* h2ab     = (float*)(ws + 139776);       // 2048 f32
    float* partials = (float*)(ws + 163840);       // 16384 f32 (ends 229376)
    unsigned short* wfT = (unsigned short*)(ws + 262144);  // 32*16384 bf16 = 1 MB

    k_zero       <<<1,    32,   0, stream>>>(gc);
    k_attn_scores<<<N_NODES/32, 256, 0, stream>>>(x, aw1, ab1, aw2, ab2, aw3, ab3, scores);
    k_softmax_red<<<1,    1024, 0, stream>>>(scores, red);
    k_attn_wf    <<<N_NODES/256, 256, 0, stream>>>(scores, red, x, attn, wfT, gc);
    k_context    <<<16384, 256, 0, stream>>>(A, wfT, x, attn, partials);
    k_mlp1       <<<1,    1024, 0, stream>>>(gc, partials, gw1, gb1, h1ab);
    k_mlp2       <<<128,  256,  0, stream>>>(h1ab, gw2, gb2, h2ab);
    k_mlp3       <<<16,   512,  0, stream>>>(h2ab, gw3, gb3, out);
}